// Round 11
// baseline (29.776 us; speedup 1.0000x reference)
//
#include <hip/hip_runtime.h>

// EntropyBottleneck fused likelihood + quantize — single-kernel, per-block LDS table.
// Round-11: overlap the table build with the memory stream. Each thread issues
// its 4 x-stream float4 loads BEFORE phases 0/1 (loads land in VGPRs and do not
// depend on the table; consumed after the 2nd barrier), so first-round HBM
// traffic flows concurrently with the ~1us trans-op build instead of after it.
// Noise loads stay after the barrier (overlap the lerp compute; caps VGPRs).
// Rest = round-10: NT=128 built by lanes 0-127 (err 1.49e-7 measured), 2048x256
// one-shot blocked layout (2048*256*16==N), plain stores (L3 absorbs).

#define NT   128
#define TLO  (-16.0f)
#define THI  ( 16.0f)

typedef float v4f __attribute__((ext_vector_type(4)));

__device__ __forceinline__ float frcp(float x) { return __builtin_amdgcn_rcpf(x); }

__device__ __forceinline__ float ftanh(float x) {
    float e = __expf(2.0f * x);
    return 1.0f - 2.0f * frcp(e + 1.0f);
}

__device__ __forceinline__ float fsigm(float x) {
    return frcp(1.0f + __expf(-x));
}

__device__ __forceinline__ float fsoftplus(float x) {
    return __logf(1.0f + __expf(x));
}

struct EBP {
    float m0[3], b0[3], t0[3];
    float m1[9], b1[3], t1[3];
    float m2[9], b2[3], t2[3];
    float m3[9], b3[3], t3[3];
    float m4[3], b4;
};

__device__ __forceinline__ float logits_cum(const EBP& p, float v) {
    float h[3], g[3];
#pragma unroll
    for (int o = 0; o < 3; o++) {
        float l = fmaf(p.m0[o], v, p.b0[o]);
        h[o] = fmaf(p.t0[o], ftanh(l), l);
    }
#pragma unroll
    for (int o = 0; o < 3; o++) {
        float l = p.b1[o];
#pragma unroll
        for (int i = 0; i < 3; i++) l = fmaf(p.m1[o * 3 + i], h[i], l);
        g[o] = fmaf(p.t1[o], ftanh(l), l);
    }
#pragma unroll
    for (int o = 0; o < 3; o++) {
        float l = p.b2[o];
#pragma unroll
        for (int i = 0; i < 3; i++) l = fmaf(p.m2[o * 3 + i], g[i], l);
        h[o] = fmaf(p.t2[o], ftanh(l), l);
    }
#pragma unroll
    for (int o = 0; o < 3; o++) {
        float l = p.b3[o];
#pragma unroll
        for (int i = 0; i < 3; i++) l = fmaf(p.m3[o * 3 + i], h[i], l);
        g[o] = fmaf(p.t3[o], ftanh(l), l);
    }
    float out = p.b4;
#pragma unroll
    for (int i = 0; i < 3; i++) out = fmaf(p.m4[i], g[i], out);
    return out;
}

__device__ __forceinline__ float eb_lik(const EBP& p, float y) {
    float l = logits_cum(p, y - 0.5f);
    float u = logits_cum(p, y + 0.5f);
    float sum = l + u;
    float sg = (sum > 0.0f) ? -1.0f : ((sum < 0.0f) ? 1.0f : 0.0f);
    float a = fsigm(sg * u);
    float b = fsigm(sg * l);
    return fmaxf(fabsf(a - b), 1e-9f);
}

// LDS param map: [0..32]=softplus(m), [33..44]=tanh(f), [45..57]=b
__global__ __launch_bounds__(256) void eb_fused(
    const float* __restrict__ x, const float* __restrict__ nz,
    const float* __restrict__ s,
    const float* __restrict__ m0_, const float* __restrict__ b0_, const float* __restrict__ f0_,
    const float* __restrict__ m1_, const float* __restrict__ b1_, const float* __restrict__ f1_,
    const float* __restrict__ m2_, const float* __restrict__ b2_, const float* __restrict__ f2_,
    const float* __restrict__ m3_, const float* __restrict__ b3_, const float* __restrict__ f3_,
    const float* __restrict__ m4_, const float* __restrict__ b4_,
    float* __restrict__ out, int n)
{
    __shared__ float P[64];
    __shared__ float tab[NT];

    const int t   = threadIdx.x;
    const int gid = blockIdx.x * blockDim.x + t;
    const int T   = gridDim.x * blockDim.x;
    const int nv4 = n >> 2;

    const v4f* __restrict__ x4 = (const v4f*)x;
    const v4f* __restrict__ n4 = (const v4f*)nz;

    // ---- issue x-stream loads FIRST: overlap with the table build below ----
    const bool oneshot = (nv4 == 4 * T);
    v4f xv[4];
    if (oneshot) {
#pragma unroll
        for (int k = 0; k < 4; k++) xv[k] = x4[gid + k * T];
    }

    // ---- phase 0: parameter transform (lanes 0-58) ----
    if (t < 33) {
        const float* src = (t < 3)  ? (m0_ + t)
                         : (t < 12) ? (m1_ + (t - 3))
                         : (t < 21) ? (m2_ + (t - 12))
                         : (t < 30) ? (m3_ + (t - 21))
                                    : (m4_ + (t - 30));
        P[t] = fsoftplus(*src);
    } else if (t < 45) {
        const int k = t - 33;
        const float* src = (k < 3) ? (f0_ + k)
                         : (k < 6) ? (f1_ + (k - 3))
                         : (k < 9) ? (f2_ + (k - 6))
                                   : (f3_ + (k - 9));
        P[t] = ftanh(*src);
    } else if (t < 58) {
        const int k = t - 45;
        const float* src = (k < 3)  ? (b0_ + k)
                         : (k < 6)  ? (b1_ + (k - 3))
                         : (k < 9)  ? (b2_ + (k - 6))
                         : (k < 12) ? (b3_ + (k - 9))
                                    : b4_;
        P[t] = *src;
    }
    __syncthreads();

    // ---- phase 1: lanes 0..NT-1 tabulate F (1 eval each) ----
    if (t < NT) {
        EBP p;
#pragma unroll
        for (int i = 0; i < 3; i++) p.m0[i] = P[i];
#pragma unroll
        for (int i = 0; i < 9; i++) p.m1[i] = P[3 + i];
#pragma unroll
        for (int i = 0; i < 9; i++) p.m2[i] = P[12 + i];
#pragma unroll
        for (int i = 0; i < 9; i++) p.m3[i] = P[21 + i];
#pragma unroll
        for (int i = 0; i < 3; i++) p.m4[i] = P[30 + i];
#pragma unroll
        for (int i = 0; i < 3; i++) { p.t0[i] = P[33 + i]; p.t1[i] = P[36 + i]; p.t2[i] = P[39 + i]; p.t3[i] = P[42 + i]; }
#pragma unroll
        for (int i = 0; i < 3; i++) { p.b0[i] = P[45 + i]; p.b1[i] = P[48 + i]; p.b2[i] = P[51 + i]; p.b3[i] = P[54 + i]; }
        p.b4 = P[57];

        const float hstep = (THI - TLO) / (float)(NT - 1);
        tab[t] = eb_lik(p, TLO + (float)t * hstep);
    }
    __syncthreads();

    // ---- phase 2: streaming pass ----
    const float sc   = fmaxf(s[0], 1e-4f);   // broadcast load, per-thread
    const float inv  = 1.0f / sc;
    const float invh = (float)(NT - 1) / (THI - TLO);
    const float qa   = inv * sc;
    const float ta   = inv * invh;
    const float tb   = -TLO * invh;
    const float tmax = (float)(NT - 1) - 1e-3f;   // floor() <= NT-2

    float* __restrict__ oq = out;
    float* __restrict__ ol = out + n;
    v4f* __restrict__ oq4 = (v4f*)oq;
    v4f* __restrict__ ol4 = (v4f*)ol;

    if (oneshot) {
        v4f nv[4];
#pragma unroll
        for (int k = 0; k < 4; k++) nv[k] = n4[gid + k * T];
#pragma unroll
        for (int k = 0; k < 4; k++) {
            const int idx = gid + k * T;
            v4f qv, lv;
#pragma unroll
            for (int j = 0; j < 4; j++) {
                qv[j] = fmaf(xv[k][j], qa, nv[k][j] * sc);
                float tt = fmaf(xv[k][j], ta, tb);
                tt = fminf(fmaxf(tt, 0.0f), tmax);
                float fi = floorf(tt);
                int ii = (int)fi;
                float f0 = tab[ii];
                float f1 = tab[ii + 1];
                lv[j] = fmaf(tt - fi, f1 - f0, f0);
            }
            oq4[idx] = qv;
            ol4[idx] = lv;
        }
    } else {
        for (int i = gid; i < nv4; i += T) {
            v4f xa = x4[i], na = n4[i];
            v4f qv, lv;
#pragma unroll
            for (int j = 0; j < 4; j++) {
                qv[j] = fmaf(xa[j], qa, na[j] * sc);
                float tt = fmaf(xa[j], ta, tb);
                tt = fminf(fmaxf(tt, 0.0f), tmax);
                float fi = floorf(tt);
                int ii = (int)fi;
                float f0 = tab[ii];
                float f1 = tab[ii + 1];
                lv[j] = fmaf(tt - fi, f1 - f0, f0);
            }
            oq4[i] = qv;
            ol4[i] = lv;
        }
    }
    // scalar tail (n % 4) — not hit for N=8388608
    for (int i = (nv4 << 2) + gid; i < n; i += T) {
        float xvs = x[i];
        oq[i] = fmaf(xvs, qa, nz[i] * sc);
        float tt = fmaf(xvs, ta, tb);
        tt = fminf(fmaxf(tt, 0.0f), tmax);
        float fi = floorf(tt);
        int ii = (int)fi;
        float f0 = tab[ii];
        float f1 = tab[ii + 1];
        ol[i] = fmaf(tt - fi, f1 - f0, f0);
    }
}

extern "C" void kernel_launch(void* const* d_in, const int* in_sizes, int n_in,
                              void* d_out, int out_size, void* d_ws, size_t ws_size,
                              hipStream_t stream) {
    const float* x  = (const float*)d_in[0];
    const float* nz = (const float*)d_in[1];
    const float* s  = (const float*)d_in[2];
    const float* m0 = (const float*)d_in[3];
    const float* b0 = (const float*)d_in[4];
    const float* f0 = (const float*)d_in[5];
    const float* m1 = (const float*)d_in[6];
    const float* b1 = (const float*)d_in[7];
    const float* f1 = (const float*)d_in[8];
    const float* m2 = (const float*)d_in[9];
    const float* b2 = (const float*)d_in[10];
    const float* f2 = (const float*)d_in[11];
    const float* m3 = (const float*)d_in[12];
    const float* b3 = (const float*)d_in[13];
    const float* f3 = (const float*)d_in[14];
    const float* m4 = (const float*)d_in[15];
    const float* b4 = (const float*)d_in[16];
    const int n = in_sizes[0];

    // 2048 blocks x 256: 8 blocks/CU, 16 elems/thread; 2048*256*16 == N exactly.
    eb_fused<<<2048, 256, 0, stream>>>(x, nz, s,
                                       m0, b0, f0, m1, b1, f1,
                                       m2, b2, f2, m3, b3, f3,
                                       m4, b4,
                                       (float*)d_out, n);
}

// Round 12
// 28.625 us; speedup vs baseline: 1.0402x; 1.0402x over previous
//
#include <hip/hip_runtime.h>

// EntropyBottleneck fused likelihood + quantize — BARRIER-FREE per-wave LDS table.
// __syncthreads costs a vmcnt(0)+lgkmcnt(0) drain and convoys the block (round-8/11
// evidence). Instead each WAVE builds its own NT=64 table in its own LDS region:
// wave-lockstep ds_write -> s_waitcnt lgkmcnt(0) -> ds_read needs no barrier.
// Lanes 0-57 transform params (1 trans op each) -> waitcnt -> each lane evals one
// table node (~52 trans ops, ~0.3us, overlapped with other waves' streaming) ->
// waitcnt -> one-shot blocked streaming pass (16 elems/thread, plain stores).
// NT=64 lerp error ~4e-7 (abs err was eps-floored 1.49e-7 at NT=256 AND NT=128,
// so curvature term is ~1e-7 at h=0.25; h=0.51 -> ~4x) << 0.216 threshold.

#define NT   64
#define TLO  (-16.0f)
#define THI  ( 16.0f)

typedef float v4f __attribute__((ext_vector_type(4)));

__device__ __forceinline__ float frcp(float x) { return __builtin_amdgcn_rcpf(x); }

__device__ __forceinline__ float ftanh(float x) {
    float e = __expf(2.0f * x);
    return 1.0f - 2.0f * frcp(e + 1.0f);
}

__device__ __forceinline__ float fsigm(float x) {
    return frcp(1.0f + __expf(-x));
}

__device__ __forceinline__ float fsoftplus(float x) {
    return __logf(1.0f + __expf(x));
}

struct EBP {
    float m0[3], b0[3], t0[3];
    float m1[9], b1[3], t1[3];
    float m2[9], b2[3], t2[3];
    float m3[9], b3[3], t3[3];
    float m4[3], b4;
};

__device__ __forceinline__ float logits_cum(const EBP& p, float v) {
    float h[3], g[3];
#pragma unroll
    for (int o = 0; o < 3; o++) {
        float l = fmaf(p.m0[o], v, p.b0[o]);
        h[o] = fmaf(p.t0[o], ftanh(l), l);
    }
#pragma unroll
    for (int o = 0; o < 3; o++) {
        float l = p.b1[o];
#pragma unroll
        for (int i = 0; i < 3; i++) l = fmaf(p.m1[o * 3 + i], h[i], l);
        g[o] = fmaf(p.t1[o], ftanh(l), l);
    }
#pragma unroll
    for (int o = 0; o < 3; o++) {
        float l = p.b2[o];
#pragma unroll
        for (int i = 0; i < 3; i++) l = fmaf(p.m2[o * 3 + i], g[i], l);
        h[o] = fmaf(p.t2[o], ftanh(l), l);
    }
#pragma unroll
    for (int o = 0; o < 3; o++) {
        float l = p.b3[o];
#pragma unroll
        for (int i = 0; i < 3; i++) l = fmaf(p.m3[o * 3 + i], h[i], l);
        g[o] = fmaf(p.t3[o], ftanh(l), l);
    }
    float out = p.b4;
#pragma unroll
    for (int i = 0; i < 3; i++) out = fmaf(p.m4[i], g[i], out);
    return out;
}

__device__ __forceinline__ float eb_lik(const EBP& p, float y) {
    float l = logits_cum(p, y - 0.5f);
    float u = logits_cum(p, y + 0.5f);
    float sum = l + u;
    float sg = (sum > 0.0f) ? -1.0f : ((sum < 0.0f) ? 1.0f : 0.0f);
    float a = fsigm(sg * u);
    float b = fsigm(sg * l);
    return fmaxf(fabsf(a - b), 1e-9f);
}

__device__ __forceinline__ void wave_lds_fence() {
    asm volatile("s_waitcnt lgkmcnt(0)" ::: "memory");
    __builtin_amdgcn_sched_barrier(0);
}

// per-wave P map: [0..32]=softplus(m), [33..44]=tanh(f), [45..57]=b
__global__ __launch_bounds__(256) void eb_fused(
    const float* __restrict__ x, const float* __restrict__ nz,
    const float* __restrict__ s,
    const float* __restrict__ m0_, const float* __restrict__ b0_, const float* __restrict__ f0_,
    const float* __restrict__ m1_, const float* __restrict__ b1_, const float* __restrict__ f1_,
    const float* __restrict__ m2_, const float* __restrict__ b2_, const float* __restrict__ f2_,
    const float* __restrict__ m3_, const float* __restrict__ b3_, const float* __restrict__ f3_,
    const float* __restrict__ m4_, const float* __restrict__ b4_,
    float* __restrict__ out, int n)
{
    __shared__ float Pw[4][64];
    __shared__ float tabw[4][NT + 4];   // +4 stagger between waves

    const int t    = threadIdx.x;
    const int wid  = t >> 6;
    const int lane = t & 63;
    float* __restrict__ P   = Pw[wid];
    float* __restrict__ tab = tabw[wid];

    const int gid = blockIdx.x * blockDim.x + t;
    const int T   = gridDim.x * blockDim.x;
    const int nv4 = n >> 2;
    const bool oneshot = (nv4 == 4 * T);

    const v4f* __restrict__ x4 = (const v4f*)x;
    const v4f* __restrict__ n4 = (const v4f*)nz;

    // ---- phase 0: per-wave param transform (lanes 0-57, ~1 trans op each) ----
    if (lane < 33) {
        const float* src = (lane < 3)  ? (m0_ + lane)
                         : (lane < 12) ? (m1_ + (lane - 3))
                         : (lane < 21) ? (m2_ + (lane - 12))
                         : (lane < 30) ? (m3_ + (lane - 21))
                                       : (m4_ + (lane - 30));
        P[lane] = fsoftplus(*src);
    } else if (lane < 45) {
        const int k = lane - 33;
        const float* src = (k < 3) ? (f0_ + k)
                         : (k < 6) ? (f1_ + (k - 3))
                         : (k < 9) ? (f2_ + (k - 6))
                                   : (f3_ + (k - 9));
        P[lane] = ftanh(*src);
    } else if (lane < 58) {
        const int k = lane - 45;
        const float* src = (k < 3)  ? (b0_ + k)
                         : (k < 6)  ? (b1_ + (k - 3))
                         : (k < 9)  ? (b2_ + (k - 6))
                         : (k < 12) ? (b3_ + (k - 9))
                                    : b4_;
        P[lane] = *src;
    }
    wave_lds_fence();

    // ---- issue x-stream loads: in flight during the table build (no barrier!) ----
    v4f xv[4];
    if (oneshot) {
#pragma unroll
        for (int k = 0; k < 4; k++) xv[k] = x4[gid + k * T];
    }

    // ---- phase 1: each lane evaluates ONE node of its wave's NT=64 table ----
    {
        EBP p;
#pragma unroll
        for (int i = 0; i < 3; i++) p.m0[i] = P[i];
#pragma unroll
        for (int i = 0; i < 9; i++) p.m1[i] = P[3 + i];
#pragma unroll
        for (int i = 0; i < 9; i++) p.m2[i] = P[12 + i];
#pragma unroll
        for (int i = 0; i < 9; i++) p.m3[i] = P[21 + i];
#pragma unroll
        for (int i = 0; i < 3; i++) p.m4[i] = P[30 + i];
#pragma unroll
        for (int i = 0; i < 3; i++) { p.t0[i] = P[33 + i]; p.t1[i] = P[36 + i]; p.t2[i] = P[39 + i]; p.t3[i] = P[42 + i]; }
#pragma unroll
        for (int i = 0; i < 3; i++) { p.b0[i] = P[45 + i]; p.b1[i] = P[48 + i]; p.b2[i] = P[51 + i]; p.b3[i] = P[54 + i]; }
        p.b4 = P[57];

        const float hstep = (THI - TLO) / (float)(NT - 1);
        tab[lane] = eb_lik(p, TLO + (float)lane * hstep);
    }
    wave_lds_fence();

    // ---- phase 2: streaming pass ----
    const float sc   = fmaxf(s[0], 1e-4f);
    const float inv  = 1.0f / sc;
    const float invh = (float)(NT - 1) / (THI - TLO);
    const float qa   = inv * sc;
    const float ta   = inv * invh;
    const float tb   = -TLO * invh;
    const float tmax = (float)(NT - 1) - 1e-3f;   // floor() <= NT-2

    float* __restrict__ oq = out;
    float* __restrict__ ol = out + n;
    v4f* __restrict__ oq4 = (v4f*)oq;
    v4f* __restrict__ ol4 = (v4f*)ol;

    if (oneshot) {
        v4f nv[4];
#pragma unroll
        for (int k = 0; k < 4; k++) nv[k] = n4[gid + k * T];
#pragma unroll
        for (int k = 0; k < 4; k++) {
            const int idx = gid + k * T;
            v4f qv, lv;
#pragma unroll
            for (int j = 0; j < 4; j++) {
                qv[j] = fmaf(xv[k][j], qa, nv[k][j] * sc);
                float tt = fmaf(xv[k][j], ta, tb);
                tt = fminf(fmaxf(tt, 0.0f), tmax);
                float fi = floorf(tt);
                int ii = (int)fi;
                float f0 = tab[ii];
                float f1 = tab[ii + 1];
                lv[j] = fmaf(tt - fi, f1 - f0, f0);
            }
            oq4[idx] = qv;
            ol4[idx] = lv;
        }
    } else {
        for (int i = gid; i < nv4; i += T) {
            v4f xa = x4[i], na = n4[i];
            v4f qv, lv;
#pragma unroll
            for (int j = 0; j < 4; j++) {
                qv[j] = fmaf(xa[j], qa, na[j] * sc);
                float tt = fmaf(xa[j], ta, tb);
                tt = fminf(fmaxf(tt, 0.0f), tmax);
                float fi = floorf(tt);
                int ii = (int)fi;
                float f0 = tab[ii];
                float f1 = tab[ii + 1];
                lv[j] = fmaf(tt - fi, f1 - f0, f0);
            }
            oq4[i] = qv;
            ol4[i] = lv;
        }
    }
    // scalar tail (n % 4) — not hit for N=8388608
    for (int i = (nv4 << 2) + gid; i < n; i += T) {
        float xvs = x[i];
        oq[i] = fmaf(xvs, qa, nz[i] * sc);
        float tt = fmaf(xvs, ta, tb);
        tt = fminf(fmaxf(tt, 0.0f), tmax);
        float fi = floorf(tt);
        int ii = (int)fi;
        float f0 = tab[ii];
        float f1 = tab[ii + 1];
        ol[i] = fmaf(tt - fi, f1 - f0, f0);
    }
}

extern "C" void kernel_launch(void* const* d_in, const int* in_sizes, int n_in,
                              void* d_out, int out_size, void* d_ws, size_t ws_size,
                              hipStream_t stream) {
    const float* x  = (const float*)d_in[0];
    const float* nz = (const float*)d_in[1];
    const float* s  = (const float*)d_in[2];
    const float* m0 = (const float*)d_in[3];
    const float* b0 = (const float*)d_in[4];
    const float* f0 = (const float*)d_in[5];
    const float* m1 = (const float*)d_in[6];
    const float* b1 = (const float*)d_in[7];
    const float* f1 = (const float*)d_in[8];
    const float* m2 = (const float*)d_in[9];
    const float* b2 = (const float*)d_in[10];
    const float* f2 = (const float*)d_in[11];
    const float* m3 = (const float*)d_in[12];
    const float* b3 = (const float*)d_in[13];
    const float* f3 = (const float*)d_in[14];
    const float* m4 = (const float*)d_in[15];
    const float* b4 = (const float*)d_in[16];
    const int n = in_sizes[0];

    // 2048 blocks x 256: 16 elems/thread; 2048*256*16 == N exactly (one-shot).
    eb_fused<<<2048, 256, 0, stream>>>(x, nz, s,
                                       m0, b0, f0, m1, b1, f1,
                                       m2, b2, f2, m3, b3, f3,
                                       m4, b4,
                                       (float*)d_out, n);
}